// Round 10
// baseline (155.428 us; speedup 1.0000x reference)
//
#include <hip/hip_runtime.h>
#include <math.h>

typedef short short8 __attribute__((ext_vector_type(8)));
typedef float float4_t __attribute__((ext_vector_type(4)));
typedef float f32x16 __attribute__((ext_vector_type(16)));
typedef unsigned short ushort_t;

#define BH   32
#define N_   2048
#define D_   64
#define NCH  32
#define KV_ELEMS (BH * N_ * D_)
// d_ws: Kf [0,8M) | Vf [8M,16M) | mskT [16M,16.5M)
#define OFF_VF  (KV_ELEMS * 2)
#define OFF_MSK (KV_ELEMS * 4)
#define QSCALE 0.18033688f      // 0.125*log2(e): exp(s/8) == exp2(s*QSCALE)

__device__ __forceinline__ unsigned pack_bf16(float a, float b) {
  union { float f; unsigned u; } ua{a}, ub{b};
  return __builtin_amdgcn_perm(ub.u + 0x8000u, ua.u + 0x8000u, 0x07060302u);
}

__device__ __forceinline__ unsigned cvt_pk_bf16(float a, float b) {
  // single-inst packed f32->bf16 (lo = a, hi = b); no builtin on gfx950
  unsigned r;
  asm("v_cvt_pk_bf16_f32 %0, %1, %2" : "=v"(r) : "v"(a), "v"(b));
  return r;
}

__device__ __forceinline__ void gload_lds16(const ushort_t* g, ushort_t* l) {
  // async global->LDS, 16B/lane, lane-linear dest (fragment-linear layout)
  __builtin_amdgcn_global_load_lds(
      (const __attribute__((address_space(1))) unsigned int*)(g),
      (__attribute__((address_space(3))) unsigned int*)(l), 16, 0, 0);
}

// ---------------- prep v7 (verified r8, unchanged): 32x32 fragment-linear Kf/Vf + mskT ----
// Kf group g = nt*4+ks  : lane(hi,l32) -> K[nt*32+l32][ks*16+hi*8+j]   (S^T A-frag)
// Vf group g = nt*4+dt*2+ksp: lane -> V[nt*32+phi][dt*32+l32],
//   phi(ksp,hi,j) = (ksp*2+(j>>2))*8 + hi*4 + (j&3)   (PV B-frag, key-permuted)
// mskT[c][row]: coalesced per-q-row u64 mask words in attn.
__global__ __launch_bounds__(256) void prep_kernel(
    const float* __restrict__ K, const float* __restrict__ V,
    const int* __restrict__ adj, ushort_t* __restrict__ Kf,
    ushort_t* __restrict__ Vf, unsigned long long* __restrict__ msk) {
  __shared__ __align__(16) float Tc[64 * 68];
  const int blk = blockIdx.x, t = threadIdx.x;

  if (blk < 2048) {
    const bool isK = blk < 1024;
    const int b = isK ? blk : blk - 1024;
    const float* src = (isK ? K : V) + (b >> 5) * (N_ * D_) + (b & 31) * 64 * D_;
#pragma unroll
    for (int i = 0; i < 4; ++i) {
      int idx = i * 256 + t;
      int row = idx >> 4, c4 = (idx & 15) * 4;
      *(float4_t*)&Tc[row * 68 + c4] = *(const float4_t*)(src + row * D_ + c4);
    }
    __syncthreads();
    ushort_t* dst = (isK ? Kf : Vf) + b * 4096;
#pragma unroll
    for (int e = 0; e < 2; ++e) {
      int u = t * 2 + e;
      int g = u >> 6, lane = u & 63;
      int hi = lane >> 5, l32 = lane & 31;
      float v[8];
      if (isK) {
        int nt = g >> 2, ks = g & 3;
        const float* rp = &Tc[(nt * 32 + l32) * 68 + ks * 16 + hi * 8];
        float4_t a = *(const float4_t*)(rp);
        float4_t bq = *(const float4_t*)(rp + 4);
#pragma unroll
        for (int j = 0; j < 4; ++j) { v[j] = a[j]; v[4 + j] = bq[j]; }
      } else {
        int nt = g >> 2, dt = (g >> 1) & 1, ksp = g & 1;
#pragma unroll
        for (int j = 0; j < 8; ++j) {
          int key = (ksp * 2 + (j >> 2)) * 8 + hi * 4 + (j & 3);
          v[j] = Tc[(nt * 32 + key) * 68 + dt * 32 + l32];
        }
      }
      union { short8 s; unsigned u4[4]; } h;
      h.u4[0] = pack_bf16(v[0], v[1]); h.u4[1] = pack_bf16(v[2], v[3]);
      h.u4[2] = pack_bf16(v[4], v[5]); h.u4[3] = pack_bf16(v[6], v[7]);
      *(short8*)(dst + u * 8) = h.s;
    }
  } else {
    const int row = (blk - 2048) * 4 + (t >> 6);
    const int lane = t & 63;
    unsigned long long keep = 0;
#pragma unroll 8
    for (int i = 0; i < 32; ++i) {
      int a = adj[row * N_ + i * 64 + lane];
      unsigned long long b = __ballot(a > 0);
      if (lane == i) keep = b;
    }
    if (lane < 32) msk[(size_t)lane * 2048 + row] = keep;   // mskT[c][row]
  }
}

// -------- main v9: v8 + cross-chunk S-pipeline --------
//   S(c+1) is computed during body(c) (K-tile c+1 already staged, NBUF=4),
//   so exp(c) starts right after the barrier on a chunk-old sacc, and the
//   S-MFMAs of c+1 drain in the MFMA pipe under exp/cvt VALU.
//   kv: 4 buffers (64 KB), epilogue xbuf aliased onto the same LDS.
__global__ __launch_bounds__(512, 4) void attn_main(
    const float* __restrict__ Q, const ushort_t* __restrict__ Kf,
    const ushort_t* __restrict__ Vf, const unsigned long long* __restrict__ msk,
    float* __restrict__ O) {
  __shared__ __align__(16) char smem[65536];       // kv[4][8192] ushort (64KB)
  ushort_t (*kv)[8192] = (ushort_t (*)[8192])smem; //   aliased by xbuf in epilogue
  float (*xbuf)[32][64] = (float (*)[32][64])smem; // [4][32][64] f32 (32KB)

  const int t    = threadIdx.x;
  const int w    = t >> 6;                  // 0..7
  const int lane = t & 63;
  const int l32  = lane & 31;
  const int hi   = lane >> 5;
  const int pair = w >> 1;                  // 0..3 : 32-row tile
  const int nt   = w & 1;                   // key half (cols nt*32..+31)
  const int bh   = blockIdx.x & (BH - 1);
  const int qt   = blockIdx.x >> 5;         // 0..15
  const int base = bh * (N_ * D_);
  const int trow0 = qt * 128 + pair * 32;   // 32 q-rows per wave pair

  const ushort_t* Kfb = Kf + (bh * 32) * 4096;
  const ushort_t* Vfb = Vf + (bh * 32) * 4096;
  const unsigned long long* mrow = msk + (trow0 + l32);   // + c*2048 per chunk

  // Q B-frags for S^T = mfma(K, Q): B[k=d][n=q]: n=l32 (q-row), k=ks*16+hi*8+j
  short8 qf[4];
#pragma unroll
  for (int ks = 0; ks < 4; ++ks) {
    const float* qp = Q + base + (trow0 + l32) * D_ + ks * 16 + hi * 8;
    float4_t f0 = *(const float4_t*)(qp);
    float4_t f1 = *(const float4_t*)(qp + 4);
    union { short8 s; unsigned u[4]; } h;
    h.u[0] = pack_bf16(f0[0] * QSCALE, f0[1] * QSCALE);
    h.u[1] = pack_bf16(f0[2] * QSCALE, f0[3] * QSCALE);
    h.u[2] = pack_bf16(f1[0] * QSCALE, f1[1] * QSCALE);
    h.u[3] = pack_bf16(f1[2] * QSCALE, f1[3] * QSCALE);
    qf[ks] = h.s;
  }

  // constant ones B-fragment (bf16 1.0) for rowsum-via-MFMA
  short8 ones;
#pragma unroll
  for (int j = 0; j < 8; ++j) ones[j] = (short)0x3F80;

  f32x16 oacc0, oacc1;  // O C-layout: col=l32 (+dt*32), row=(reg&3)+8*(reg>>2)+4*hi
  f32x16 osacc;         // rowsum of masked P, same row mapping as oacc
#pragma unroll
  for (int i = 0; i < 16; ++i) { oacc0[i] = 0.f; oacc1[i] = 0.f; osacc[i] = 0.f; }

  const int fo = lane * 8;    // lane-linear fragment offset (16B/lane)

  // cooperative stage of chunk c into kv[nb]: wave w moves bytes [w*2KB, +2KB)
#define STAGE(nb, c)                                                          \
  do {                                                                        \
    const ushort_t* _s = (w < 4 ? Kfb + (c)*4096 + w * 1024                   \
                                : Vfb + (c)*4096 + (w - 4) * 1024) + lane * 8;\
    ushort_t* _d = &kv[nb][w * 1024];                                         \
    gload_lds16(_s, _d);                                                      \
    gload_lds16(_s + 512, _d + 512);                                          \
  } while (0)

  // S^T for chunk cc from kv buffer: 4 ds_read + 4 MFMA into SACC
#define SCOMP(SACC, cc)                                                       \
  do {                                                                        \
    const ushort_t* _kb = &kv[(cc) & 3][0];                                   \
    _Pragma("unroll") for (int _i = 0; _i < 16; ++_i) SACC[_i] = 0.f;         \
    _Pragma("unroll") for (int _ks = 0; _ks < 4; ++_ks) {                     \
      short8 _kfr = *(const short8*)(_kb + (nt * 4 + _ks) * 512 + fo);        \
      SACC = __builtin_amdgcn_mfma_f32_32x32x16_bf16(_kfr, qf[_ks], SACC, 0, 0, 0); \
    }                                                                         \
  } while (0)

  // body(c): barrier; mask(c); stage(c+2); S(c+1)->SNEXT; exp(c) on SCUR; PV(c)
#define BODY(c, SCUR, SNEXT)                                                  \
  {                                                                           \
    __syncthreads();  /* vmcnt(0)+lgkmcnt(0): stage(c),(c+1) landed block-wide */ \
    unsigned long long mw = mrow[(size_t)(c) * 2048];                         \
    if ((c) + 2 < NCH) STAGE(((c) + 2) & 3, (c) + 2);                         \
    if ((c) + 1 < NCH) SCOMP(SNEXT, (c) + 1);                                 \
    unsigned half = (unsigned)(nt ? (mw >> 32) : mw);                         \
    half >>= (hi << 2);                                                       \
    float p[16];                                                              \
    _Pragma("unroll") for (int reg = 0; reg < 16; ++reg) {                    \
      const int pos = (reg & 3) + 8 * (reg >> 2);                             \
      int sm = ((int)(half << (31 - pos))) >> 31;                             \
      union { float f; unsigned u; } e;                                       \
      e.f = __builtin_amdgcn_exp2f(SCUR[reg]);                                \
      e.u &= (unsigned)sm;                                                    \
      p[reg] = e.f;                                                           \
    }                                                                         \
    union { short8 s; unsigned u[4]; } pa0, pa1;                              \
    _Pragma("unroll") for (int jj = 0; jj < 4; ++jj) {                        \
      int r = (jj >> 1) * 4 + (jj & 1) * 2;                                   \
      pa0.u[jj] = cvt_pk_bf16(p[r], p[r + 1]);                                \
      pa1.u[jj] = cvt_pk_bf16(p[8 + r], p[8 + r + 1]);                        \
    }                                                                         \
    const ushort_t* vb = &kv[(c) & 3][4096];                                  \
    short8 v00 = *(const short8*)(vb + (nt * 4 + 0) * 512 + fo);              \
    short8 v01 = *(const short8*)(vb + (nt * 4 + 1) * 512 + fo);              \
    short8 v10 = *(const short8*)(vb + (nt * 4 + 2) * 512 + fo);              \
    short8 v11 = *(const short8*)(vb + (nt * 4 + 3) * 512 + fo);              \
    oacc0 = __builtin_amdgcn_mfma_f32_32x32x16_bf16(pa0.s, v00, oacc0, 0, 0, 0); \
    oacc0 = __builtin_amdgcn_mfma_f32_32x32x16_bf16(pa1.s, v01, oacc0, 0, 0, 0); \
    oacc1 = __builtin_amdgcn_mfma_f32_32x32x16_bf16(pa0.s, v10, oacc1, 0, 0, 0); \
    oacc1 = __builtin_amdgcn_mfma_f32_32x32x16_bf16(pa1.s, v11, oacc1, 0, 0, 0); \
    osacc = __builtin_amdgcn_mfma_f32_32x32x16_bf16(pa0.s, ones, osacc, 0, 0, 0); \
    osacc = __builtin_amdgcn_mfma_f32_32x32x16_bf16(pa1.s, ones, osacc, 0, 0, 0); \
  }

  // prologue: stage chunks 0,1; drain; precompute S(0)
  STAGE(0, 0);
  STAGE(1, 1);
  __syncthreads();
  f32x16 saccA, saccB;
  SCOMP(saccA, 0);

  for (int c = 0; c < NCH; c += 2) {
    BODY(c,     saccA, saccB);   // uses S(c)=saccA, computes S(c+1)->saccB
    BODY(c + 1, saccB, saccA);   // uses saccB, computes S(c+2)->saccA
  }

  // ---- epilogue (v8, xbuf aliased onto kv): combine nt halves, normalize ----
  __syncthreads();
  if (nt) {
#pragma unroll
    for (int reg = 0; reg < 16; ++reg) {
      xbuf[pair][reg][lane]      = oacc0[reg];
      xbuf[pair][16 + reg][lane] = osacc[reg];
    }
  }
  __syncthreads();
  float invv[16];
  if (!nt) {
#pragma unroll
    for (int reg = 0; reg < 16; ++reg) {
      invv[reg] = 1.f / (osacc[reg] + xbuf[pair][16 + reg][lane]);
      oacc0[reg] = (oacc0[reg] + xbuf[pair][reg][lane]) * invv[reg];
    }
  }
  __syncthreads();
  if (nt) {
#pragma unroll
    for (int reg = 0; reg < 16; ++reg) xbuf[pair][reg][lane] = oacc1[reg];
  }
  __syncthreads();
  if (!nt) {
#pragma unroll
    for (int reg = 0; reg < 16; ++reg) {
      int qo = (reg & 3) + 8 * (reg >> 2) + 4 * hi;     // output q-row
      O[base + (trow0 + qo) * D_ + l32]      = oacc0[reg];
      O[base + (trow0 + qo) * D_ + 32 + l32] =
          (oacc1[reg] + xbuf[pair][reg][lane]) * invv[reg];
    }
  }
}

extern "C" void kernel_launch(void* const* d_in, const int* in_sizes, int n_in,
                              void* d_out, int out_size, void* d_ws, size_t ws_size,
                              hipStream_t stream) {
  const float* Q  = (const float*)d_in[0];
  const float* K  = (const float*)d_in[1];
  const float* V  = (const float*)d_in[2];
  const int* adj  = (const int*)d_in[3];
  float* O        = (float*)d_out;
  ushort_t* Kf    = (ushort_t*)d_ws;
  ushort_t* Vf    = (ushort_t*)((char*)d_ws + OFF_VF);
  unsigned long long* msk = (unsigned long long*)((char*)d_ws + OFF_MSK);

  prep_kernel<<<2560, 256, 0, stream>>>(K, V, adj, Kf, Vf, msk);
  attn_main<<<512, 512, 0, stream>>>(Q, Kf, Vf, msk, O);   // 4096 waves, 16/CU
}